// Round 1
// baseline (123.892 us; speedup 1.0000x reference)
//
#include <hip/hip_runtime.h>

// ---- types ----------------------------------------------------------------
typedef __attribute__((ext_vector_type(8))) short bf16x8;     // 8 bf16 (4 VGPR)
typedef __attribute__((ext_vector_type(4))) float f32x4;
typedef __attribute__((ext_vector_type(4))) unsigned short us4;

#define MFMA(a, b, c) __builtin_amdgcn_mfma_f32_16x16x32_bf16((a), (b), (c), 0, 0, 0)

__device__ __forceinline__ unsigned short f2bf(float f) {
  unsigned u = __builtin_bit_cast(unsigned, f);
  u = (u + 0x7fffu + ((u >> 16) & 1u)) >> 16;  // RNE
  return (unsigned short)u;
}

__device__ __forceinline__ void gload16(const void* g, void* l) {
  __builtin_amdgcn_global_load_lds((const __attribute__((address_space(1))) void*)g,
                                   (__attribute__((address_space(3))) void*)l,
                                   16, 0, 0);
}

// ---- kernel 1: cast x -> bf16 (float4 vectorized) --------------------------
__global__ void cast_x_kernel(const float* __restrict__ x,
                              unsigned short* __restrict__ xb, int n4) {
  int id = blockIdx.x * blockDim.x + threadIdx.x;
  if (id >= n4) return;
  float4 v = ((const float4*)x)[id];
  us4 o = { f2bf(v.x), f2bf(v.y), f2bf(v.z), f2bf(v.w) };
  ((us4*)xb)[id] = o;
}

// ---- kernel 2: W [768][2304] -> Wt [2304][768] bf16 (tiled transpose) ------
__global__ void castw_kernel(const float* __restrict__ W,
                             unsigned short* __restrict__ Wt) {
  __shared__ unsigned short tile[32][33];
  int bn = blockIdx.x * 32;  // n-tile
  int bk = blockIdx.y * 32;  // k-tile
  int lx = threadIdx.x & 31, ly = threadIdx.x >> 5;  // 32 x 8
#pragma unroll
  for (int i = 0; i < 32; i += 8)
    tile[ly + i][lx] = f2bf(W[(bk + ly + i) * 2304 + bn + lx]);
  __syncthreads();
#pragma unroll
  for (int i = 0; i < 32; i += 8)
    Wt[(bn + ly + i) * 768 + bk + lx] = tile[lx][ly + i];
}

// ---- kernel 3: QKV GEMM ----------------------------------------------------
// C[8192,2304] = x_bf16[8192,768] @ W[768,2304] + bias ; scatter to q/k/v bf16
// q,k: [B,H,T,64]; v transposed: [B,H,64,T]
__global__ __launch_bounds__(256) void qkv_gemm_kernel(
    const unsigned short* __restrict__ xb, const unsigned short* __restrict__ wt,
    const float* __restrict__ bias,
    unsigned short* __restrict__ qb, unsigned short* __restrict__ kb,
    unsigned short* __restrict__ vb) {
  __shared__ unsigned short lA[128 * 64];  // [m][k]
  __shared__ unsigned short lB[128 * 64];  // [n][k]  (Wt rows)
  const int tid = threadIdx.x;
  const int lane = tid & 63, wid = tid >> 6;
  const int wm = wid >> 1, wn = wid & 1;
  const int l15 = lane & 15, lg = lane >> 4;
  const int n0 = blockIdx.x * 128;
  const int m0 = blockIdx.y * 128;

  f32x4 acc[4][4] = {};

  for (int kt = 0; kt < 12; ++kt) {
    const int k0 = kt * 64;
#pragma unroll
    for (int r = 0; r < 4; ++r) {
      int idx = r * 256 + tid;
      int row = idx >> 3, c8 = (idx & 7) << 3;
      gload16(xb + (m0 + row) * 768 + k0 + c8, &lA[idx * 8]);
      gload16(wt + (n0 + row) * 768 + k0 + c8, &lB[idx * 8]);
    }
    __syncthreads();
#pragma unroll
    for (int kk = 0; kk < 2; ++kk) {
      bf16x8 a[4], b[4];
#pragma unroll
      for (int mf = 0; mf < 4; ++mf)
        a[mf] = *(const bf16x8*)&lA[(wm * 64 + mf * 16 + l15) * 64 + kk * 32 + lg * 8];
#pragma unroll
      for (int nf = 0; nf < 4; ++nf)
        b[nf] = *(const bf16x8*)&lB[(wn * 64 + nf * 16 + l15) * 64 + kk * 32 + lg * 8];
#pragma unroll
      for (int mf = 0; mf < 4; ++mf)
#pragma unroll
        for (int nf = 0; nf < 4; ++nf)
          acc[mf][nf] = MFMA(a[mf], b[nf], acc[mf][nf]);
    }
    __syncthreads();
  }

  // epilogue: bias + cast + scatter. n-tiles never cross q/k/v boundary.
  const int sec = n0 / 768;  // 0=q, 1=k, 2=v (block-uniform)
  float bcol[4];
#pragma unroll
  for (int nf = 0; nf < 4; ++nf) bcol[nf] = bias[n0 + wn * 64 + nf * 16 + l15];

#pragma unroll
  for (int nf = 0; nf < 4; ++nf) {
    int col = n0 + wn * 64 + nf * 16 + l15;
    int cc = col - sec * 768;
    int h = cc >> 6, d = cc & 63;
#pragma unroll
    for (int mf = 0; mf < 4; ++mf) {
      int row0 = m0 + wm * 64 + mf * 16 + lg * 4;  // 4 consecutive rows, same batch
      int bb = row0 >> 10;
      int t0 = row0 & 1023;
      if (sec < 2) {
        unsigned short* dst =
            (sec == 0 ? qb : kb) + (size_t)(((bb * 12 + h) << 10) + t0) * 64 + d;
#pragma unroll
        for (int r = 0; r < 4; ++r) dst[r * 64] = f2bf(acc[mf][nf][r] + bcol[nf]);
      } else {
        us4 o;
#pragma unroll
        for (int r = 0; r < 4; ++r) o[r] = f2bf(acc[mf][nf][r] + bcol[nf]);
        *(us4*)(vb + (size_t)((bb * 12 + h) * 64 + d) * 1024 + t0) = o;  // 8B store
      }
    }
  }
}

// ---- kernel 4: causal ReLU attention --------------------------------------
// per block: one (b,h), 64 q-rows; 4 waves x 16 rows each.
__global__ __launch_bounds__(256) void attn_kernel(
    const unsigned short* __restrict__ qb, const unsigned short* __restrict__ kb,
    const unsigned short* __restrict__ vb, float* __restrict__ out) {
  __shared__ unsigned short ldsK[64 * 64];  // [key][d]
  __shared__ unsigned short ldsV[64 * 64];  // [d][key]   (v stored transposed)
  __shared__ unsigned short ldsS[64 * 72];  // [qrow][key], pad 8 -> 144B rows
  const int tid = threadIdx.x;
  const int lane = tid & 63, wid = tid >> 6;
  const int l15 = lane & 15, lg = lane >> 4;
  const int bh = blockIdx.x;           // b*12+h
  const int q0 = blockIdx.y * 64;
  const int b = bh / 12, h = bh % 12;
  const size_t base = (size_t)bh * 65536;  // 1024*64 per (b,h)

  // Q fragments live in registers for the whole block
  const unsigned short* qp = qb + base + (size_t)(q0 + wid * 16 + l15) * 64 + lg * 8;
  bf16x8 aq[2];
  aq[0] = *(const bf16x8*)qp;
  aq[1] = *(const bf16x8*)(qp + 32);

  f32x4 o[4] = {};

  const int nkt = (q0 >> 6) + 1;  // causal: only tiles at or below the diagonal
  for (int kt = 0; kt < nkt; ++kt) {
#pragma unroll
    for (int r = 0; r < 2; ++r) {
      int idx = r * 256 + tid;
      gload16(kb + base + kt * 4096 + idx * 8, &ldsK[idx * 8]);
      gload16(vb + base + (idx >> 3) * 1024 + kt * 64 + ((idx & 7) << 3),
              &ldsV[idx * 8]);
    }
    __syncthreads();

    // S = q @ k^T  (fp32 acc)
    f32x4 s[4] = {};
#pragma unroll
    for (int kk = 0; kk < 2; ++kk)
#pragma unroll
      for (int nf = 0; nf < 4; ++nf) {
        bf16x8 bk = *(const bf16x8*)&ldsK[(nf * 16 + l15) * 64 + kk * 32 + lg * 8];
        s[nf] = MFMA(aq[kk], bk, s[nf]);
      }

    // scale * relu * causal-mask -> bf16 in LDS
#pragma unroll
    for (int nf = 0; nf < 4; ++nf) {
      int col = nf * 16 + l15;
      int gk = kt * 64 + col;
#pragma unroll
      for (int r = 0; r < 4; ++r) {
        int qrow = wid * 16 + lg * 4 + r;
        float v = s[nf][r] * 0.125f;
        v = (gk <= q0 + qrow) ? fmaxf(v, 0.0f) : 0.0f;
        ldsS[qrow * 72 + col] = f2bf(v);
      }
    }
    __syncthreads();

    // O += S @ V
#pragma unroll
    for (int kk = 0; kk < 2; ++kk) {
      bf16x8 as = *(const bf16x8*)&ldsS[(wid * 16 + l15) * 72 + kk * 32 + lg * 8];
#pragma unroll
      for (int df = 0; df < 4; ++df) {
        bf16x8 bv = *(const bf16x8*)&ldsV[(df * 16 + l15) * 64 + kk * 32 + lg * 8];
        o[df] = MFMA(as, bv, o[df]);
      }
    }
    __syncthreads();
  }

  // write O: out[b][t][h*64+d], fp32
#pragma unroll
  for (int df = 0; df < 4; ++df) {
    int d = df * 16 + l15;
#pragma unroll
    for (int r = 0; r < 4; ++r) {
      int t = q0 + wid * 16 + lg * 4 + r;
      out[(size_t)(b * 1024 + t) * 768 + h * 64 + d] = o[df][r];
    }
  }
}

// ---- launch ----------------------------------------------------------------
extern "C" void kernel_launch(void* const* d_in, const int* in_sizes, int n_in,
                              void* d_out, int out_size, void* d_ws, size_t ws_size,
                              hipStream_t stream) {
  const float* x = (const float*)d_in[0];     // [8,1024,768]
  const float* W = (const float*)d_in[1];     // [768,2304]
  const float* bias = (const float*)d_in[2];  // [2304]
  float* out = (float*)d_out;                 // [8,1024,768]

  // workspace layout (bf16), all 16B-aligned
  unsigned short* xb = (unsigned short*)d_ws;  // 6291456
  unsigned short* wt = xb + 6291456;           // 1769472 (Wt [2304][768])
  unsigned short* qb = wt + 1769472;           // [B,H,T,64]
  unsigned short* kb = qb + 6291456;           // [B,H,T,64]
  unsigned short* vb = kb + 6291456;           // [B,H,64,T]

  cast_x_kernel<<<6144, 256, 0, stream>>>(x, xb, 1572864);
  castw_kernel<<<dim3(72, 24), 256, 0, stream>>>(W, wt);
  qkv_gemm_kernel<<<dim3(18, 64), 256, 0, stream>>>(xb, wt, bias, qb, kb, vb);
  attn_kernel<<<dim3(96, 16), 256, 0, stream>>>(qb, kb, vb, out);
}

// Round 2
// 102.674 us; speedup vs baseline: 1.2067x; 1.2067x over previous
//
#include <hip/hip_runtime.h>

// ---- types ----------------------------------------------------------------
typedef __attribute__((ext_vector_type(8))) short bf16x8;     // 8 bf16 (4 VGPR)
typedef __attribute__((ext_vector_type(4))) float f32x4;
typedef __attribute__((ext_vector_type(4))) unsigned short us4;
typedef __attribute__((ext_vector_type(8))) unsigned short us8;

#define MFMA(a, b, c) __builtin_amdgcn_mfma_f32_16x16x32_bf16((a), (b), (c), 0, 0, 0)

__device__ __forceinline__ unsigned short f2bf(float f) {
  unsigned u = __builtin_bit_cast(unsigned, f);
  u = (u + 0x7fffu + ((u >> 16) & 1u)) >> 16;  // RNE
  return (unsigned short)u;
}

__device__ __forceinline__ void gload16(const void* g, void* l) {
  __builtin_amdgcn_global_load_lds((const __attribute__((address_space(1))) void*)g,
                                   (__attribute__((address_space(3))) void*)l,
                                   16, 0, 0);
}

// swizzled fragment read: rows are 128B apart; phys = byte ^ ((row&7)<<4)
// (involution; spreads the 16-lane column read across all 8 bank-quads)
__device__ __forceinline__ bf16x8 readfrag(const unsigned short* buf, int row, int kbyte) {
  int byte = row * 128 + kbyte;
  byte ^= (row & 7) << 4;
  return *(const bf16x8*)((const char*)buf + byte);
}

// ---- kernel 1: cast x -> bf16 (float4 vectorized) --------------------------
__global__ void cast_x_kernel(const float* __restrict__ x,
                              unsigned short* __restrict__ xb, int n4) {
  int id = blockIdx.x * blockDim.x + threadIdx.x;
  if (id >= n4) return;
  float4 v = ((const float4*)x)[id];
  us4 o = { f2bf(v.x), f2bf(v.y), f2bf(v.z), f2bf(v.w) };
  ((us4*)xb)[id] = o;
}

// ---- kernel 2: W [768][2304] -> Wt [2304][768] bf16 (tiled transpose) ------
__global__ void castw_kernel(const float* __restrict__ W,
                             unsigned short* __restrict__ Wt) {
  __shared__ unsigned short tile[32][33];
  int bn = blockIdx.x * 32;
  int bk = blockIdx.y * 32;
  int lx = threadIdx.x & 31, ly = threadIdx.x >> 5;  // 32 x 8
#pragma unroll
  for (int i = 0; i < 32; i += 8)
    tile[ly + i][lx] = f2bf(W[(bk + ly + i) * 2304 + bn + lx]);
  __syncthreads();
#pragma unroll
  for (int i = 0; i < 32; i += 8)
    Wt[(bn + ly + i) * 768 + bk + lx] = tile[lx][ly + i];
}

// ---- kernel 3: QKV GEMM (pipelined, counted vmcnt) -------------------------
// C[8192,2304] = x_bf16[8192,768] @ W[768,2304] + bias ; scatter to q/k/v bf16
// BM=256 BN=128 BK=64, 8 waves (4Mx2N, 64x64 each). A 3-deep, B 2-deep LDS.
__global__ __launch_bounds__(512, 2) void qkv_gemm_kernel(
    const unsigned short* __restrict__ xb, const unsigned short* __restrict__ wt,
    const float* __restrict__ bias,
    unsigned short* __restrict__ qb, unsigned short* __restrict__ kb,
    unsigned short* __restrict__ vb) {
  __shared__ unsigned short lds[65536];  // 128 KB: A 3x16384 elems @0, B 2x8192 @49152
  const int tid = threadIdx.x;
  const int lane = tid & 63, wid = tid >> 6;
  const int wm = wid >> 1, wn = wid & 1;
  const int l15 = lane & 15, lg = lane >> 4;

  // XCD-aware swizzle: 576 blocks = 8 XCDs x 72. XCD grid (4m x 2n), each owns
  // an 8mb x 9nb region (A panel 3MB + B panel 1.7MB ~ fits 4MB L2).
  int bid = blockIdx.x;
  int xcd = bid & 7, c = bid >> 3;
  int mb = (xcd & 3) * 8 + (c & 7);
  int nb = (xcd >> 2) * 9 + (c >> 3);
  const int m0 = mb * 256, n0 = nb * 128;

  const unsigned short* Ab_g = xb + (size_t)m0 * 768;
  const unsigned short* Bb_g = wt + (size_t)n0 * 768;

  // stage addressing: linear LDS dest, inverse-swizzled global source
  int eA[4], sA[4], eB[2], sB[2];
#pragma unroll
  for (int i = 0; i < 4; ++i) {
    int e = (i * 512 + tid) * 8, row = e >> 6;
    eA[i] = e;
    sA[i] = row * 768 + ((e ^ ((row & 7) << 3)) & 63);
  }
#pragma unroll
  for (int i = 0; i < 2; ++i) {
    int e = (i * 512 + tid) * 8, row = e >> 6;
    eB[i] = e;
    sB[i] = row * 768 + ((e ^ ((row & 7) << 3)) & 63);
  }

#define SA(buf, k0, i) gload16(Ab_g + sA[i] + (k0), &lds[(buf) * 16384 + eA[i]])
#define SB(buf, k0, i) gload16(Bb_g + sB[i] + (k0), &lds[49152 + (buf) * 8192 + eB[i]])

  f32x4 acc[4][4] = {};
  bf16x8 bfr[4][2];

  // prologue: A(0) x4, B(0) x2, A(1) x4 -> wait first 6 (allow newest 4)
  SA(0, 0, 0); SA(0, 0, 1); SA(0, 0, 2); SA(0, 0, 3);
  SB(0, 0, 0); SB(0, 0, 1);
  SA(1, 64, 0); SA(1, 64, 1); SA(1, 64, 2); SA(1, 64, 3);
  asm volatile("s_waitcnt vmcnt(4)" ::: "memory");
  __builtin_amdgcn_s_barrier();

// phase: ds_read subtile -> issue stage -> barrier -> lgkmcnt(0) -> 16 MFMA -> [vmcnt] -> barrier
#define GPHASE(cA_, cB_, Q, STG, EW)                                              \
  {                                                                               \
    const unsigned short* Abuf = &lds[(cA_) * 16384];                             \
    const unsigned short* Bbuf = &lds[49152 + (cB_) * 8192];                      \
    bf16x8 afr[2][2];                                                             \
    _Pragma("unroll") for (int m2 = 0; m2 < 2; ++m2)                              \
        _Pragma("unroll") for (int kk = 0; kk < 2; ++kk)                          \
            afr[m2][kk] =                                                         \
        readfrag(Abuf, wm * 64 + ((Q) * 2 + m2) * 16 + l15, kk * 64 + lg * 16);   \
    if ((Q) == 0) {                                                               \
      _Pragma("unroll") for (int nf = 0; nf < 4; ++nf)                            \
          _Pragma("unroll") for (int kk = 0; kk < 2; ++kk)                        \
              bfr[nf][kk] =                                                       \
          readfrag(Bbuf, wn * 64 + nf * 16 + l15, kk * 64 + lg * 16);             \
    }                                                                             \
    STG;                                                                          \
    __builtin_amdgcn_sched_barrier(0);                                            \
    __builtin_amdgcn_s_barrier();                                                 \
    asm volatile("s_waitcnt lgkmcnt(0)" ::: "memory");                            \
    __builtin_amdgcn_sched_barrier(0);                                            \
    __builtin_amdgcn_s_setprio(1);                                                \
    _Pragma("unroll") for (int m2 = 0; m2 < 2; ++m2)                              \
        _Pragma("unroll") for (int nf = 0; nf < 4; ++nf)                          \
            _Pragma("unroll") for (int kk = 0; kk < 2; ++kk)                      \
                acc[(Q) * 2 + m2][nf] =                                           \
        MFMA(afr[m2][kk], bfr[nf][kk], acc[(Q) * 2 + m2][nf]);                    \
    __builtin_amdgcn_s_setprio(0);                                                \
    EW;                                                                           \
    __builtin_amdgcn_sched_barrier(0);                                            \
    __builtin_amdgcn_s_barrier();                                                 \
  }

  // main loop: iter kt consumes A[kt%3],B[kt&1]; stages B(kt+1), A(kt+2).
  // end-of-iter vmcnt(4): newest 4 = A(kt+2); drains B(kt+1) and A(kt+1).
  int cA = 0;
  for (int kt = 0; kt < 10; ++kt) {
    int cB = kt & 1, cBn = cB ^ 1;
    int cA2 = cA + 2; if (cA2 >= 3) cA2 -= 3;
    int k1 = (kt + 1) * 64, k2 = (kt + 2) * 64;
    GPHASE(cA, cB, 0,
           { SB(cBn, k1, 0); SB(cBn, k1, 1); SA(cA2, k2, 0); SA(cA2, k2, 1); }, );
    GPHASE(cA, cB, 1, { SA(cA2, k2, 2); SA(cA2, k2, 3); },
           asm volatile("s_waitcnt vmcnt(4)" ::: "memory"));
    cA = (cA == 2) ? 0 : cA + 1;
  }
  // kt=10: stage only B(11); end: drain all
  GPHASE(cA, 0, 0, { SB(1, 704, 0); SB(1, 704, 1); }, );
  GPHASE(cA, 0, 1, ,
         asm volatile("s_waitcnt vmcnt(0)" ::: "memory"));
  cA = (cA == 2) ? 0 : cA + 1;
  // kt=11
  GPHASE(cA, 1, 0, , );
  GPHASE(cA, 1, 1, , );

  __syncthreads();  // full drain; reuse LDS for epilogue

  const int sec = n0 / 768;  // 0=q,1=k,2=v (block-uniform; 128 | 768)
  float bcol[4];
#pragma unroll
  for (int nf = 0; nf < 4; ++nf) bcol[nf] = bias[n0 + wn * 64 + nf * 16 + l15];

  if (sec < 2) {
    // LDS roundtrip -> coalesced us8 stores
    unsigned short* ct = lds;  // [256][128]
#pragma unroll
    for (int mf = 0; mf < 4; ++mf)
#pragma unroll
      for (int nf = 0; nf < 4; ++nf)
#pragma unroll
        for (int r = 0; r < 4; ++r)
          ct[(wm * 64 + mf * 16 + lg * 4 + r) * 128 + wn * 64 + nf * 16 + l15] =
              f2bf(acc[mf][nf][r] + bcol[nf]);
    __syncthreads();
    unsigned short* dstbase = (sec == 0) ? qb : kb;
    const int hbase = (n0 - sec * 768) >> 6;
    const int g8 = tid >> 3, l8 = tid & 7;
#pragma unroll
    for (int j = 0; j < 8; ++j) {
      int chunk = j * 64 + g8;  // 0..511 = row*2 + hh
      int row = chunk >> 1, hh = chunk & 1;
      us8 v = *(const us8*)&ct[row * 128 + hh * 64 + l8 * 8];
      int t = m0 + row, bb = t >> 10, tt = t & 1023;
      *(us8*)(dstbase + ((size_t)((bb * 12 + hbase + hh) * 1024 + tt)) * 64 + l8 * 8) = v;
    }
  } else {
    // v transposed [B,H,64,T]: us4 stores along t
#pragma unroll
    for (int nf = 0; nf < 4; ++nf) {
      int cc = (n0 - 1536) + wn * 64 + nf * 16 + l15;
      int h = cc >> 6, d = cc & 63;
#pragma unroll
      for (int mf = 0; mf < 4; ++mf) {
        int row0 = m0 + wm * 64 + mf * 16 + lg * 4;
        int bb = row0 >> 10, t0 = row0 & 1023;
        us4 o;
#pragma unroll
        for (int r = 0; r < 4; ++r) o[r] = f2bf(acc[mf][nf][r] + bcol[nf]);
        *(us4*)(vb + ((size_t)((bb * 12 + h) * 64 + d)) * 1024 + t0) = o;
      }
    }
  }
#undef SA
#undef SB
#undef GPHASE
}

// ---- kernel 4: causal ReLU attention (K/V LDS now swizzled) ----------------
__global__ __launch_bounds__(256) void attn_kernel(
    const unsigned short* __restrict__ qb, const unsigned short* __restrict__ kb,
    const unsigned short* __restrict__ vb, float* __restrict__ out) {
  __shared__ unsigned short ldsK[64 * 64];  // [key][d], swizzled
  __shared__ unsigned short ldsV[64 * 64];  // [d][key], swizzled
  __shared__ unsigned short ldsS[64 * 72];  // [qrow][key], pad to 144B rows
  const int tid = threadIdx.x;
  const int lane = tid & 63, wid = tid >> 6;
  const int l15 = lane & 15, lg = lane >> 4;
  const int bh = blockIdx.x;
  const int q0 = blockIdx.y * 64;
  const int b = bh / 12, h = bh % 12;
  const size_t base = (size_t)bh * 65536;

  const unsigned short* qp = qb + base + (size_t)(q0 + wid * 16 + l15) * 64 + lg * 8;
  bf16x8 aq[2];
  aq[0] = *(const bf16x8*)qp;
  aq[1] = *(const bf16x8*)(qp + 32);

  f32x4 o[4] = {};

  const int nkt = (q0 >> 6) + 1;
  for (int kt = 0; kt < nkt; ++kt) {
#pragma unroll
    for (int r = 0; r < 2; ++r) {
      int e = (r * 256 + tid) * 8;
      int row = e >> 6;
      int esw = e ^ ((row & 7) << 3);  // inverse-swizzled source, linear dest
      gload16(kb + base + kt * 4096 + esw, &ldsK[e]);
      gload16(vb + base + (size_t)row * 1024 + kt * 64 + (esw & 63), &ldsV[e]);
    }
    __syncthreads();

    // S = q @ k^T  (fp32 acc)
    f32x4 s[4] = {};
#pragma unroll
    for (int kk = 0; kk < 2; ++kk)
#pragma unroll
      for (int nf = 0; nf < 4; ++nf) {
        bf16x8 bk = readfrag(ldsK, nf * 16 + l15, kk * 64 + lg * 16);
        s[nf] = MFMA(aq[kk], bk, s[nf]);
      }

    // scale * relu * causal-mask -> bf16 in LDS
#pragma unroll
    for (int nf = 0; nf < 4; ++nf) {
      int col = nf * 16 + l15;
      int gk = kt * 64 + col;
#pragma unroll
      for (int r = 0; r < 4; ++r) {
        int qrow = wid * 16 + lg * 4 + r;
        float v = s[nf][r] * 0.125f;
        v = (gk <= q0 + qrow) ? fmaxf(v, 0.0f) : 0.0f;
        ldsS[qrow * 72 + col] = f2bf(v);
      }
    }
    __syncthreads();

    // O += S @ V
#pragma unroll
    for (int kk = 0; kk < 2; ++kk) {
      bf16x8 as = *(const bf16x8*)&ldsS[(wid * 16 + l15) * 72 + kk * 32 + lg * 8];
#pragma unroll
      for (int df = 0; df < 4; ++df) {
        bf16x8 bv = readfrag(ldsV, df * 16 + l15, kk * 64 + lg * 16);
        o[df] = MFMA(as, bv, o[df]);
      }
    }
    __syncthreads();
  }

#pragma unroll
  for (int df = 0; df < 4; ++df) {
    int d = df * 16 + l15;
#pragma unroll
    for (int r = 0; r < 4; ++r) {
      int t = q0 + wid * 16 + lg * 4 + r;
      out[(size_t)(b * 1024 + t) * 768 + h * 64 + d] = o[df][r];
    }
  }
}

// ---- launch ----------------------------------------------------------------
extern "C" void kernel_launch(void* const* d_in, const int* in_sizes, int n_in,
                              void* d_out, int out_size, void* d_ws, size_t ws_size,
                              hipStream_t stream) {
  const float* x = (const float*)d_in[0];
  const float* W = (const float*)d_in[1];
  const float* bias = (const float*)d_in[2];
  float* out = (float*)d_out;

  unsigned short* xb = (unsigned short*)d_ws;  // 6291456 elems
  unsigned short* wt = xb + 6291456;           // 1769472 (Wt [2304][768])
  unsigned short* qb = wt + 1769472;           // [B,H,T,64]
  unsigned short* kb = qb + 6291456;
  unsigned short* vb = kb + 6291456;           // [B,H,64,T]

  cast_x_kernel<<<6144, 256, 0, stream>>>(x, xb, 1572864);
  castw_kernel<<<dim3(72, 24), 256, 0, stream>>>(W, wt);
  qkv_gemm_kernel<<<576, 512, 0, stream>>>(xb, wt, bias, qb, kb, vb);
  attn_kernel<<<dim3(96, 16), 256, 0, stream>>>(qb, kb, vb, out);
}